// Round 13
// baseline (265.291 us; speedup 1.0000x reference)
//
#include <hip/hip_runtime.h>
#include <math.h>

typedef _Float16 f16;
typedef _Float16 f16x2 __attribute__((ext_vector_type(2)));
typedef _Float16 f16x4 __attribute__((ext_vector_type(4)));
typedef _Float16 f16x8 __attribute__((ext_vector_type(8)));
typedef float    f32x4 __attribute__((ext_vector_type(4)));

#define NB 4096
#define LT 512
#define NC 16
#define NS 32

// workspace layout (bytes)
#define WS_P0     0                     // 32 f32, softmax(init)*256
#define WS_SIG    128                   // 32 f32, sigmoid(acc)*256
#define WS_SUMSIG 256                   // 1 f32
#define WS_FWDT   512                   // 16384 f16 = 32768 B
#define WS_BWDT   (512 + 32768)
#define WS_F      (512 + 65536)         // 32*4096 f32
#define WS_G      (WS_F + 32*4096*4)

#if __has_builtin(__builtin_amdgcn_exp2f)
#define EXP2F __builtin_amdgcn_exp2f
#else
#define EXP2F exp2f
#endif

// ---------------- prep: softmaxes + fragment tables (exchange-free layout) ----
// K=512 flattening: k-slot (chunk kc, octet q, elem j) <-> source state
// st(q,j) = 4q + (j&3) + 16*(j>>2), symbol c = kc.  (st is exactly the state
// set lane (q,*) holds in the 16x16x32 D-layout: rows 4q..4q+3 of each half.)
// A-frag [kc][r] at lane (q,m): elem j = T[st(q,j)][kc][16r+m]   (fwd: dest=n)
// bwd swaps roles: dest = p (rows), source = n:   elem j = T[16r+m][kc][st(q,j)]
__global__ __launch_bounds__(512) void pdfa_prep(const float* __restrict__ tlogit,
                                                 const float* __restrict__ ilogit,
                                                 const float* __restrict__ alogit,
                                                 char* __restrict__ ws) {
    int tid = threadIdx.x;           // 512 threads = one (p,c) row each
    f16* fwdT = (f16*)(ws + WS_FWDT);
    f16* bwdT = (f16*)(ws + WS_BWDT);
    int p = tid >> 4, c = tid & 15;
    const float* row = tlogit + p * 512 + c * 32;
    float mx = row[0];
    for (int n = 1; n < 32; ++n) mx = fmaxf(mx, row[n]);
    float s = 0.f;
    for (int n = 0; n < 32; ++n) s += expf(row[n] - mx);
    float inv = 1.f / s;
    for (int n = 0; n < 32; ++n) {
        float tv = expf(row[n] - mx) * inv;
        // fwd: source p -> (q,j); dest n -> (r,m); chunk = c
        {
            int q = (p & 15) >> 2, j = (p & 3) + 4 * (p >> 4);
            int r = n >> 4, m = n & 15;
            fwdT[((c * 2 + r) * 64 + 16 * q + m) * 8 + j] = (f16)tv;
        }
        // bwd: source n -> (q,j); dest p -> (r,m); chunk = c
        {
            int q = (n & 15) >> 2, j = (n & 3) + 4 * (n >> 4);
            int r = p >> 4, m = p & 15;
            bwdT[((c * 2 + r) * 64 + 16 * q + m) * 8 + j] = (f16)tv;
        }
    }
    if (tid < 32) {
        float m0 = ilogit[0];
        for (int n = 1; n < 32; ++n) m0 = fmaxf(m0, ilogit[n]);
        float s0 = 0.f;
        for (int n = 0; n < 32; ++n) s0 += expf(ilogit[n] - m0);
        ((float*)(ws + WS_P0))[tid]  = 256.f * expf(ilogit[tid] - m0) / s0;
        ((float*)(ws + WS_SIG))[tid] = 256.f / (1.f + expf(-alogit[tid]));
    }
    if (tid == 0) {
        float ss = 0.f;
        for (int n = 0; n < 32; ++n) ss += 1.f / (1.f + expf(-alogit[n]));
        *(float*)(ws + WS_SUMSIG) = ss;
    }
}

// ---------------- main: 512 single-wave chains, 8 chains/block -> 2 waves/SIMD
#define EC(v) ((f16)EXP2F((v) * 1.44269504089f))

__global__ __launch_bounds__(512, 2) void pdfa_main(const float* __restrict__ login,
                                                    char* __restrict__ ws) {
    const int tid  = threadIdx.x;
    const int wv   = tid >> 6;              // wave within block (independent chain)
    const int lane = tid & 63;
    const int q    = lane >> 4;             // octet / D-row group
    const int col  = lane & 15;             // batch column within 16-wide tile
    const int cid  = blockIdx.x * 8 + wv;   // global chain id
    const int dir  = cid & 1;               // 0 = fwd (t 0..255), 1 = bwd (t 511..256)
    const int b0   = (cid >> 1) << 4;

    // full A-table for this dir: 32 frags x 16 B = 128 VGPRs
    const char* tblb = ws + (dir ? WS_BWDT : WS_FWDT);
    f16x8 af[16][2];
#pragma unroll
    for (int kc = 0; kc < 16; ++kc)
#pragma unroll
        for (int r = 0; r < 2; ++r)
            af[kc][r] = *(const f16x8*)(tblb + ((kc * 2 + r) * 64 + lane) * 16);

    // running state held as this lane's 8 D-output states:
    // pvec[j] = p[4q + (j&3) + 16*(j>>2)]
    const float* initv = (const float*)(ws + (dir ? WS_SIG : WS_P0));
    f32x4 pr0, pr1;
#pragma unroll
    for (int j = 0; j < 4; ++j) { pr0[j] = initv[4 * q + j]; pr1[j] = initv[16 + 4 * q + j]; }
    f16x8 pvec = {(f16)pr0[0], (f16)pr0[1], (f16)pr0[2], (f16)pr0[3],
                  (f16)pr1[0], (f16)pr1[1], (f16)pr1[2], (f16)pr1[3]};

    // raw x for this lane's column (4 lanes/col redundant -> HW-merged loads)
    const float* xg = login + (size_t)(b0 + col) * (LT * NC);
    const f32x4 z4{};
    f32x4 rn[4];
    f16x8 xq0, xq1;

#define TT(S)  (dir ? (511 - (S)) : (S))
#define TTC(S) TT((((S) > 511) ? 511 : (S)))
    {   // prologue: x-hat(t0) -> xq, raw(t1) -> rn
        const f32x4* sp = (const f32x4*)(xg + (size_t)TT(0) * NC);
        f32x4 r0 = sp[0], r1 = sp[1], r2 = sp[2], r3 = sp[3];
        xq0 = f16x8{EC(r0[0]), EC(r0[1]), EC(r0[2]), EC(r0[3]),
                    EC(r1[0]), EC(r1[1]), EC(r1[2]), EC(r1[3])};
        xq1 = f16x8{EC(r2[0]), EC(r2[1]), EC(r2[2]), EC(r2[3]),
                    EC(r3[0]), EC(r3[1]), EC(r3[2]), EC(r3[3])};
        const f32x4* sp1 = (const f32x4*)(xg + (size_t)TT(1) * NC);
        rn[0] = sp1[0]; rn[1] = sp1[1]; rn[2] = sp1[2]; rn[3] = sp1[3];
    }

    for (int s = 0; s < 256; ++s) {
        // 32 MFMAs: 8 acc chains (4 per row-half), dep distance = 8 issues
        f32x4 a0[4], a1[4];
        __builtin_amdgcn_s_setprio(1);
#pragma unroll
        for (int kc = 0; kc < 16; ++kc) {
            f16 xs = (kc < 8) ? xq0[kc & 7] : xq1[kc & 7];
            f16x8 bs = {xs, xs, xs, xs, xs, xs, xs, xs};
            f16x8 bf = pvec * bs;
            if (kc < 4) {
                a0[kc & 3] = __builtin_amdgcn_mfma_f32_16x16x32_f16(af[kc][0], bf, z4, 0, 0, 0);
                a1[kc & 3] = __builtin_amdgcn_mfma_f32_16x16x32_f16(af[kc][1], bf, z4, 0, 0, 0);
            } else {
                a0[kc & 3] = __builtin_amdgcn_mfma_f32_16x16x32_f16(af[kc][0], bf, a0[kc & 3], 0, 0, 0);
                a1[kc & 3] = __builtin_amdgcn_mfma_f32_16x16x32_f16(af[kc][1], bf, a1[kc & 3], 0, 0, 0);
            }
        }
        __builtin_amdgcn_s_setprio(0);

        // off-critical-path: convert raw(t=s+1) -> x-hat, prefetch raw(t=s+2)
        f16x8 xn0 = f16x8{EC(rn[0][0]), EC(rn[0][1]), EC(rn[0][2]), EC(rn[0][3]),
                          EC(rn[1][0]), EC(rn[1][1]), EC(rn[1][2]), EC(rn[1][3])};
        f16x8 xn1 = f16x8{EC(rn[2][0]), EC(rn[2][1]), EC(rn[2][2]), EC(rn[2][3]),
                          EC(rn[3][0]), EC(rn[3][1]), EC(rn[3][2]), EC(rn[3][3])};
        {
            const f32x4* sp = (const f32x4*)(xg + (size_t)TTC(s + 2) * NC);
            rn[0] = sp[0]; rn[1] = sp[1]; rn[2] = sp[2]; rn[3] = sp[3];
        }

        // reduce 8 accs -> new state, repack to f16
        pr0 = (a0[0] + a0[1]) + (a0[2] + a0[3]);
        pr1 = (a1[0] + a1[1]) + (a1[2] + a1[3]);
        pvec = f16x8{(f16)pr0[0], (f16)pr0[1], (f16)pr0[2], (f16)pr0[3],
                     (f16)pr1[0], (f16)pr1[1], (f16)pr1[2], (f16)pr1[3]};
        xq0 = xn0; xq1 = xn1;
    }
#undef TT
#undef TTC

    // final p -> f or g, laid out [state][b]; lane holds states 4q+j / 16+4q+j
    float* outv = (float*)(ws + (dir ? WS_G : WS_F));
#pragma unroll
    for (int j = 0; j < 4; ++j) {
        outv[(size_t)(4 * q + j) * NB + b0 + col]      = pr0[j];
        outv[(size_t)(16 + 4 * q + j) * NB + b0 + col] = pr1[j];
    }
}

// ---------------- combine: out[b] = log( f.g / 65536 + 1e-20*sum(sigma) ) ------
__global__ __launch_bounds__(256) void pdfa_combine(const char* __restrict__ ws,
                                                    float* __restrict__ out) {
    int b = blockIdx.x * 256 + threadIdx.x;
    const float* f = (const float*)(ws + WS_F);
    const float* g = (const float*)(ws + WS_G);
    float ss = *(const float*)(ws + WS_SUMSIG);
    float dot = 0.f;
#pragma unroll
    for (int s2 = 0; s2 < 32; ++s2)
        dot = fmaf(f[s2 * NB + b], g[s2 * NB + b], dot);
    out[b] = logf(dot * (1.f / 65536.f) + 1e-20f * ss);
}

extern "C" void kernel_launch(void* const* d_in, const int* in_sizes, int n_in,
                              void* d_out, int out_size, void* d_ws, size_t ws_size,
                              hipStream_t stream) {
    const float* login = (const float*)d_in[0];
    const float* ilog  = (const float*)d_in[1];
    const float* tlog  = (const float*)d_in[2];
    const float* alog  = (const float*)d_in[3];
    char* ws = (char*)d_ws;

    pdfa_prep<<<1, 512, 0, stream>>>(tlog, ilog, alog, ws);
    pdfa_main<<<64, 512, 0, stream>>>(login, ws);
    pdfa_combine<<<NB / 256, 256, 0, stream>>>(ws, (float*)d_out);
}

// Round 14
// 189.427 us; speedup vs baseline: 1.4005x; 1.4005x over previous
//
#include <hip/hip_runtime.h>
#include <math.h>

typedef _Float16 f16;
typedef _Float16 f16x2 __attribute__((ext_vector_type(2)));
typedef _Float16 f16x4 __attribute__((ext_vector_type(4)));
typedef _Float16 f16x8 __attribute__((ext_vector_type(8)));
typedef float    f32x4 __attribute__((ext_vector_type(4)));

#define NB 4096
#define LT 512
#define NC 16
#define NS 32

// workspace layout (bytes)
#define WS_P0     0                     // 32 f32, softmax(init)*256
#define WS_SIG    128                   // 32 f32, sigmoid(acc)*256
#define WS_SUMSIG 256                   // 1 f32
#define WS_FWDT   512                   // 16384 f16 = 32768 B
#define WS_BWDT   (512 + 32768)
#define WS_F      (512 + 65536)         // 32*4096 f32
#define WS_G      (WS_F + 32*4096*4)

#if __has_builtin(__builtin_amdgcn_exp2f)
#define EXP2F __builtin_amdgcn_exp2f
#else
#define EXP2F exp2f
#endif

// ---------------- prep: softmaxes + fragment tables (exchange-free layout) ----
// K=512 flattening: k-slot (chunk kc, octet q, elem j) <-> source state
// st(q,j) = 4q + (j&3) + 16*(j>>2), symbol c = kc.  (st is exactly the state
// set lane (q,*) holds in the 16x16x32 D-layout: rows 4q..4q+3 of each half.)
// A-frag [kc][r] at lane (q,m): elem j = T[st(q,j)][kc][16r+m]   (fwd: dest=n)
// bwd swaps roles: dest = p (rows), source = n:   elem j = T[16r+m][kc][st(q,j)]
__global__ __launch_bounds__(512) void pdfa_prep(const float* __restrict__ tlogit,
                                                 const float* __restrict__ ilogit,
                                                 const float* __restrict__ alogit,
                                                 char* __restrict__ ws) {
    int tid = threadIdx.x;           // 512 threads = one (p,c) row each
    f16* fwdT = (f16*)(ws + WS_FWDT);
    f16* bwdT = (f16*)(ws + WS_BWDT);
    int p = tid >> 4, c = tid & 15;
    const float* row = tlogit + p * 512 + c * 32;
    float mx = row[0];
    for (int n = 1; n < 32; ++n) mx = fmaxf(mx, row[n]);
    float s = 0.f;
    for (int n = 0; n < 32; ++n) s += expf(row[n] - mx);
    float inv = 1.f / s;
    for (int n = 0; n < 32; ++n) {
        float tv = expf(row[n] - mx) * inv;
        // fwd: source p -> (q,j); dest n -> (r,m); chunk = c
        {
            int q = (p & 15) >> 2, j = (p & 3) + 4 * (p >> 4);
            int r = n >> 4, m = n & 15;
            fwdT[((c * 2 + r) * 64 + 16 * q + m) * 8 + j] = (f16)tv;
        }
        // bwd: source n -> (q,j); dest p -> (r,m); chunk = c
        {
            int q = (n & 15) >> 2, j = (n & 3) + 4 * (n >> 4);
            int r = p >> 4, m = p & 15;
            bwdT[((c * 2 + r) * 64 + 16 * q + m) * 8 + j] = (f16)tv;
        }
    }
    if (tid < 32) {
        float m0 = ilogit[0];
        for (int n = 1; n < 32; ++n) m0 = fmaxf(m0, ilogit[n]);
        float s0 = 0.f;
        for (int n = 0; n < 32; ++n) s0 += expf(ilogit[n] - m0);
        ((float*)(ws + WS_P0))[tid]  = 256.f * expf(ilogit[tid] - m0) / s0;
        ((float*)(ws + WS_SIG))[tid] = 256.f / (1.f + expf(-alogit[tid]));
    }
    if (tid == 0) {
        float ss = 0.f;
        for (int n = 0; n < 32; ++n) ss += 1.f / (1.f + expf(-alogit[n]));
        *(float*)(ws + WS_SUMSIG) = ss;
    }
}

// ---------------- main: 512 single-wave chains, 16 MFMA chains of depth 2 -----
#define EC(v) ((f16)EXP2F((v) * 1.44269504089f))

__global__ __launch_bounds__(64, 1) void pdfa_main(const float* __restrict__ login,
                                                   char* __restrict__ ws) {
    const int lane = threadIdx.x;
    const int q    = lane >> 4;             // octet / D-row group
    const int col  = lane & 15;             // batch column within 16-wide tile
    const int bid  = blockIdx.x;
    const int dir  = bid & 1;               // 0 = fwd (t 0..255), 1 = bwd (t 511..256)
    const int b0   = (bid >> 1) << 4;

    // full A-table for this dir: 32 frags x 16 B = 128 VGPRs
    const char* tblb = ws + (dir ? WS_BWDT : WS_FWDT);
    f16x8 af[16][2];
#pragma unroll
    for (int kc = 0; kc < 16; ++kc)
#pragma unroll
        for (int r = 0; r < 2; ++r)
            af[kc][r] = *(const f16x8*)(tblb + ((kc * 2 + r) * 64 + lane) * 16);

    // running state held as this lane's 8 D-output states:
    // pvec[j] = p[4q + (j&3) + 16*(j>>2)]
    const float* initv = (const float*)(ws + (dir ? WS_SIG : WS_P0));
    f32x4 pr0, pr1;
#pragma unroll
    for (int j = 0; j < 4; ++j) { pr0[j] = initv[4 * q + j]; pr1[j] = initv[16 + 4 * q + j]; }
    f16x8 pvec = {(f16)pr0[0], (f16)pr0[1], (f16)pr0[2], (f16)pr0[3],
                  (f16)pr1[0], (f16)pr1[1], (f16)pr1[2], (f16)pr1[3]};

    // raw x for this lane's column (4 lanes/col redundant -> HW-merged loads)
    const float* xg = login + (size_t)(b0 + col) * (LT * NC);
    const f32x4 z4{};
    f32x4 rn[4];
    f16x8 xq0, xq1;

#define TT(S)  (dir ? (511 - (S)) : (S))
#define TTC(S) TT((((S) > 511) ? 511 : (S)))
    {   // prologue: x-hat(t0) -> xq, raw(t1) -> rn
        const f32x4* sp = (const f32x4*)(xg + (size_t)TT(0) * NC);
        f32x4 r0 = sp[0], r1 = sp[1], r2 = sp[2], r3 = sp[3];
        xq0 = f16x8{EC(r0[0]), EC(r0[1]), EC(r0[2]), EC(r0[3]),
                    EC(r1[0]), EC(r1[1]), EC(r1[2]), EC(r1[3])};
        xq1 = f16x8{EC(r2[0]), EC(r2[1]), EC(r2[2]), EC(r2[3]),
                    EC(r3[0]), EC(r3[1]), EC(r3[2]), EC(r3[3])};
        const f32x4* sp1 = (const f32x4*)(xg + (size_t)TT(1) * NC);
        rn[0] = sp1[0]; rn[1] = sp1[1]; rn[2] = sp1[2]; rn[3] = sp1[3];
    }

    for (int s = 0; s < 256; ++s) {
        // 32 MFMAs as 16 independent chains of depth 2 (8 per row-half).
        // First 16 issues: kc=0..7, C=0. Second 16: kc=8..15 chain into them.
        // Dependent distance = 16 MFMA issues (~310 cyc) >= D->C latency.
        f32x4 a0[8], a1[8];
        __builtin_amdgcn_s_setprio(1);
#pragma unroll
        for (int kc = 0; kc < 8; ++kc) {
            f16 xs = xq0[kc];
            f16x8 bs = {xs, xs, xs, xs, xs, xs, xs, xs};
            f16x8 bf = pvec * bs;
            a0[kc] = __builtin_amdgcn_mfma_f32_16x16x32_f16(af[kc][0], bf, z4, 0, 0, 0);
            a1[kc] = __builtin_amdgcn_mfma_f32_16x16x32_f16(af[kc][1], bf, z4, 0, 0, 0);
        }
#pragma unroll
        for (int kc = 8; kc < 16; ++kc) {
            f16 xs = xq1[kc & 7];
            f16x8 bs = {xs, xs, xs, xs, xs, xs, xs, xs};
            f16x8 bf = pvec * bs;
            a0[kc & 7] = __builtin_amdgcn_mfma_f32_16x16x32_f16(af[kc][0], bf, a0[kc & 7], 0, 0, 0);
            a1[kc & 7] = __builtin_amdgcn_mfma_f32_16x16x32_f16(af[kc][1], bf, a1[kc & 7], 0, 0, 0);
        }
        __builtin_amdgcn_s_setprio(0);

        // off-critical-path: convert raw(t=s+1) -> x-hat, prefetch raw(t=s+2)
        f16x8 xn0 = f16x8{EC(rn[0][0]), EC(rn[0][1]), EC(rn[0][2]), EC(rn[0][3]),
                          EC(rn[1][0]), EC(rn[1][1]), EC(rn[1][2]), EC(rn[1][3])};
        f16x8 xn1 = f16x8{EC(rn[2][0]), EC(rn[2][1]), EC(rn[2][2]), EC(rn[2][3]),
                          EC(rn[3][0]), EC(rn[3][1]), EC(rn[3][2]), EC(rn[3][3])};
        {
            const f32x4* sp = (const f32x4*)(xg + (size_t)TTC(s + 2) * NC);
            rn[0] = sp[0]; rn[1] = sp[1]; rn[2] = sp[2]; rn[3] = sp[3];
        }

        // reduce 8+8 accs -> new state, repack to f16
        pr0 = ((a0[0] + a0[1]) + (a0[2] + a0[3])) + ((a0[4] + a0[5]) + (a0[6] + a0[7]));
        pr1 = ((a1[0] + a1[1]) + (a1[2] + a1[3])) + ((a1[4] + a1[5]) + (a1[6] + a1[7]));
        pvec = f16x8{(f16)pr0[0], (f16)pr0[1], (f16)pr0[2], (f16)pr0[3],
                     (f16)pr1[0], (f16)pr1[1], (f16)pr1[2], (f16)pr1[3]};
        xq0 = xn0; xq1 = xn1;
    }
#undef TT
#undef TTC

    // final p -> f or g, laid out [state][b]; lane holds states 4q+j / 16+4q+j
    float* outv = (float*)(ws + (dir ? WS_G : WS_F));
#pragma unroll
    for (int j = 0; j < 4; ++j) {
        outv[(size_t)(4 * q + j) * NB + b0 + col]      = pr0[j];
        outv[(size_t)(16 + 4 * q + j) * NB + b0 + col] = pr1[j];
    }
}

// ---------------- combine: out[b] = log( f.g / 65536 + 1e-20*sum(sigma) ) ------
__global__ __launch_bounds__(256) void pdfa_combine(const char* __restrict__ ws,
                                                    float* __restrict__ out) {
    int b = blockIdx.x * 256 + threadIdx.x;
    const float* f = (const float*)(ws + WS_F);
    const float* g = (const float*)(ws + WS_G);
    float ss = *(const float*)(ws + WS_SUMSIG);
    float dot = 0.f;
#pragma unroll
    for (int s2 = 0; s2 < 32; ++s2)
        dot = fmaf(f[s2 * NB + b], g[s2 * NB + b], dot);
    out[b] = logf(dot * (1.f / 65536.f) + 1e-20f * ss);
}

extern "C" void kernel_launch(void* const* d_in, const int* in_sizes, int n_in,
                              void* d_out, int out_size, void* d_ws, size_t ws_size,
                              hipStream_t stream) {
    const float* login = (const float*)d_in[0];
    const float* ilog  = (const float*)d_in[1];
    const float* tlog  = (const float*)d_in[2];
    const float* alog  = (const float*)d_in[3];
    char* ws = (char*)d_ws;

    pdfa_prep<<<1, 512, 0, stream>>>(tlog, ilog, alog, ws);
    pdfa_main<<<512, 64, 0, stream>>>(login, ws);
    pdfa_combine<<<NB / 256, 256, 0, stream>>>(ws, (float*)d_out);
}

// Round 15
// 172.939 us; speedup vs baseline: 1.5340x; 1.0953x over previous
//
#include <hip/hip_runtime.h>
#include <math.h>

typedef _Float16 f16;
typedef _Float16 f16x2 __attribute__((ext_vector_type(2)));
typedef _Float16 f16x4 __attribute__((ext_vector_type(4)));
typedef _Float16 f16x8 __attribute__((ext_vector_type(8)));
typedef float    f32x2 __attribute__((ext_vector_type(2)));
typedef float    f32x4 __attribute__((ext_vector_type(4)));

#define NB 4096
#define LT 512
#define NC 16
#define NS 32

// workspace layout (bytes)
#define WS_P0     0                     // 32 f32, softmax(init)*256
#define WS_SIG    128                   // 32 f32, sigmoid(acc)*256
#define WS_SUMSIG 256                   // 1 f32
#define WS_FWDT   512                   // 16384 f16 = 32768 B
#define WS_BWDT   (512 + 32768)
#define WS_F      (512 + 65536)         // 32*4096 f32
#define WS_G      (WS_F + 32*4096*4)

#if __has_builtin(__builtin_amdgcn_exp2f)
#define EXP2F __builtin_amdgcn_exp2f
#else
#define EXP2F exp2f
#endif

// ---------------- prep: softmaxes + fragment tables for K-split-2 -------------
// Wave w (of 2) owns source states {16w..16w+15}; its K=256 = 8 chunks of 32.
// k-slot (q = lane>>4, j): src = 16w + 4q + (j&3), symbol c = 2kc + (j>>2).
// Two row-half MFMAs r (dest rows 16r..16r+15); A[m = lane&15][k = 8q + j].
// fwd: source = p, dest = n.   bwd: source = n, dest = p.
__global__ __launch_bounds__(512) void pdfa_prep(const float* __restrict__ tlogit,
                                                 const float* __restrict__ ilogit,
                                                 const float* __restrict__ alogit,
                                                 char* __restrict__ ws) {
    int tid = threadIdx.x;           // 512 threads = one (p,c) row each
    f16* fwdT = (f16*)(ws + WS_FWDT);
    f16* bwdT = (f16*)(ws + WS_BWDT);
    int p = tid >> 4, c = tid & 15;
    const float* row = tlogit + p * 512 + c * 32;
    float mx = row[0];
    for (int n = 1; n < 32; ++n) mx = fmaxf(mx, row[n]);
    float s = 0.f;
    for (int n = 0; n < 32; ++n) s += expf(row[n] - mx);
    float inv = 1.f / s;
    for (int n = 0; n < 32; ++n) {
        float tv = expf(row[n] - mx) * inv;
        // fwd: source p -> (w,q,jlo), c -> (kc,jhi), dest n -> (r,m)
        {
            int w = p >> 4, q = (p >> 2) & 3, kc = c >> 1, r = n >> 4;
            int lane = q * 16 + (n & 15);
            int j = (p & 3) + 4 * (c & 1);
            fwdT[(((w * 8 + kc) * 2 + r) * 64 + lane) * 8 + j] = (f16)tv;
        }
        // bwd: source n -> (w,q,jlo), c -> (kc,jhi), dest p -> (r,m)
        {
            int w = n >> 4, q = (n >> 2) & 3, kc = c >> 1, r = p >> 4;
            int lane = q * 16 + (p & 15);
            int j = (n & 3) + 4 * (c & 1);
            bwdT[(((w * 8 + kc) * 2 + r) * 64 + lane) * 8 + j] = (f16)tv;
        }
    }
    if (tid < 32) {
        float m0 = ilogit[0];
        for (int n = 1; n < 32; ++n) m0 = fmaxf(m0, ilogit[n]);
        float s0 = 0.f;
        for (int n = 0; n < 32; ++n) s0 += expf(ilogit[n] - m0);
        ((float*)(ws + WS_P0))[tid]  = 256.f * expf(ilogit[tid] - m0) / s0;
        ((float*)(ws + WS_SIG))[tid] = 256.f / (1.f + expf(-alogit[tid]));
    }
    if (tid == 0) {
        float ss = 0.f;
        for (int n = 0; n < 32; ++n) ss += 1.f / (1.f + expf(-alogit[n]));
        *(float*)(ws + WS_SUMSIG) = ss;
    }
}

// ---------------- main: 512 chains x 2 waves (K-split-2), 1 wave/SIMD ---------
#define EC(v) ((f16)EXP2F((v) * 1.44269504089f))

// LDS: partials [phase 2][wave 2][64 lanes][16 B] = 4096 B
//      xbuf     [phase 2][16 col][40 B]           = 1280 B
#define XOFF 4096
#define XB   640

__global__ __launch_bounds__(128, 2) void pdfa_main(const float* __restrict__ login,
                                                    char* __restrict__ ws) {
    __shared__ __align__(16) char lds[4096 + 2 * XB];
    const int tid  = threadIdx.x;
    const int w    = tid >> 6;              // 0/1: wave = source half (16w..16w+15)
    const int lane = tid & 63;
    const int q    = lane >> 4;             // k-octet / D row group
    const int col  = lane & 15;             // batch column within 16-wide tile
    const int bid  = blockIdx.x;
    const int dir  = bid & 1;               // 0 = fwd (t 0..255), 1 = bwd (t 511..256)
    const int b0   = (bid >> 1) << 4;

    // this wave's 16 A-frags [kc][r], 16 x 16B = 64 VGPRs
    const char* tblb = ws + (dir ? WS_BWDT : WS_FWDT);
    f16x8 af[8][2];
#pragma unroll
    for (int kc = 0; kc < 8; ++kc)
#pragma unroll
        for (int r = 0; r < 2; ++r)
            af[kc][r] = *(const f16x8*)(tblb + (((w * 8 + kc) * 2 + r) * 64 + lane) * 16);

    // running state: lane's 8 D-states, pnew[jj] = p[4q + (jj&3) + 16*(jj>>2)]
    const float* initv = (const float*)(ws + (dir ? WS_SIG : WS_P0));
    f16x8 pnew;
#pragma unroll
    for (int jj = 0; jj < 8; ++jj)
        pnew[jj] = (f16)initv[4 * q + (jj & 3) + 16 * (jj >> 2)];

    // x-hat producer: thread -> (pcol = tid>>3, cpair = tid&7), 2 values/step
    const int pcol = tid >> 3, cp = tid & 7;
    const float* xg = login + (size_t)(b0 + pcol) * (LT * NC) + 2 * cp;
    char* xw = lds + XOFF + pcol * 40 + cp * 4;
    const char* xr = lds + XOFF + col * 40;

    char* pw = lds + (w * 64 + lane) * 16;            // own partial slot
    const char* prd = lds + ((1 - w) * 64 + lane) * 16; // partner slot

    const f32x4 z4{};
    f32x2 rb;

#define TT(S)  (dir ? (511 - (S)) : (S))
#define TTC(S) TT((((S) > 511) ? 511 : (S)))
    {   // prologue: x-hat(t0) -> xbuf[0]; raw(t1) -> rb
        f32x2 r0 = *(const f32x2*)(xg + (size_t)TT(0) * NC);
        *(f16x2*)(xw) = f16x2{EC(r0[0]), EC(r0[1])};
        rb = *(const f32x2*)(xg + (size_t)TT(1) * NC);
    }
    __syncthreads();
    f16x8 xqlo = *(const f16x8*)(xr);
    f16x8 xqhi = *(const f16x8*)(xr + 16);

    for (int s = 0; s < 256; ++s) {
        const int ph = s & 1;
        // own-half state quad (wave 0: lo, wave 1: hi)
        f16x4 phh = w ? f16x4{pnew[4], pnew[5], pnew[6], pnew[7]}
                      : f16x4{pnew[0], pnew[1], pnew[2], pnew[3]};
        f32x4 a0[4], a1[4];
        __builtin_amdgcn_s_setprio(1);
#pragma unroll
        for (int kc = 0; kc < 8; ++kc) {
            f16 xa = (kc < 4) ? xqlo[2 * kc]     : xqhi[2 * (kc - 4)];
            f16 xb = (kc < 4) ? xqlo[2 * kc + 1] : xqhi[2 * (kc - 4) + 1];
            f16x8 bf = {phh[0] * xa, phh[1] * xa, phh[2] * xa, phh[3] * xa,
                        phh[0] * xb, phh[1] * xb, phh[2] * xb, phh[3] * xb};
            if (kc < 4) {
                a0[kc] = __builtin_amdgcn_mfma_f32_16x16x32_f16(af[kc][0], bf, z4, 0, 0, 0);
                a1[kc] = __builtin_amdgcn_mfma_f32_16x16x32_f16(af[kc][1], bf, z4, 0, 0, 0);
            } else {
                a0[kc - 4] = __builtin_amdgcn_mfma_f32_16x16x32_f16(af[kc][0], bf, a0[kc - 4], 0, 0, 0);
                a1[kc - 4] = __builtin_amdgcn_mfma_f32_16x16x32_f16(af[kc][1], bf, a1[kc - 4], 0, 0, 0);
            }
        }
        __builtin_amdgcn_s_setprio(0);

        // independent work fills the MFMA drain: produce x-hat(s+1), load raw(s+2)
        *(f16x2*)(xw + (ph ^ 1) * XB) = f16x2{EC(rb[0]), EC(rb[1])};
        rb = *(const f32x2*)(xg + (size_t)TTC(s + 2) * NC);

        // reduce own partial, pack f16, exchange with partner wave
        f32x4 pr0 = (a0[0] + a0[1]) + (a0[2] + a0[3]);
        f32x4 pr1 = (a1[0] + a1[1]) + (a1[2] + a1[3]);
        f16x8 mine = {(f16)pr0[0], (f16)pr0[1], (f16)pr0[2], (f16)pr0[3],
                      (f16)pr1[0], (f16)pr1[1], (f16)pr1[2], (f16)pr1[3]};
        *(f16x8*)(pw + ph * 2048) = mine;
        __syncthreads();
        f16x8 other = *(const f16x8*)(prd + ph * 2048);
        xqlo = *(const f16x8*)(xr + (ph ^ 1) * XB);
        xqhi = *(const f16x8*)(xr + (ph ^ 1) * XB + 16);
        pnew = mine + other;
    }
#undef TT
#undef TTC

    // final p -> f or g, [state][b]; lane holds states 4q+i and 16+4q+i
    if (w == 0) {
        float* outv = (float*)(ws + (dir ? WS_G : WS_F));
#pragma unroll
        for (int i = 0; i < 4; ++i) {
            outv[(size_t)(4 * q + i) * NB + b0 + col]      = (float)pnew[i];
            outv[(size_t)(16 + 4 * q + i) * NB + b0 + col] = (float)pnew[4 + i];
        }
    }
}

// ---------------- combine: out[b] = log( f.g / 65536 + 1e-20*sum(sigma) ) ------
__global__ __launch_bounds__(256) void pdfa_combine(const char* __restrict__ ws,
                                                    float* __restrict__ out) {
    int b = blockIdx.x * 256 + threadIdx.x;
    const float* f = (const float*)(ws + WS_F);
    const float* g = (const float*)(ws + WS_G);
    float ss = *(const float*)(ws + WS_SUMSIG);
    float dot = 0.f;
#pragma unroll
    for (int s2 = 0; s2 < 32; ++s2)
        dot = fmaf(f[s2 * NB + b], g[s2 * NB + b], dot);
    out[b] = logf(dot * (1.f / 65536.f) + 1e-20f * ss);
}

extern "C" void kernel_launch(void* const* d_in, const int* in_sizes, int n_in,
                              void* d_out, int out_size, void* d_ws, size_t ws_size,
                              hipStream_t stream) {
    const float* login = (const float*)d_in[0];
    const float* ilog  = (const float*)d_in[1];
    const float* tlog  = (const float*)d_in[2];
    const float* alog  = (const float*)d_in[3];
    char* ws = (char*)d_ws;

    pdfa_prep<<<1, 512, 0, stream>>>(tlog, ilog, alog, ws);
    pdfa_main<<<512, 128, 0, stream>>>(login, ws);
    pdfa_combine<<<NB / 256, 256, 0, stream>>>(ws, (float*)d_out);
}